// Round 5
// baseline (504.606 us; speedup 1.0000x reference)
//
#include <hip/hip_runtime.h>
#include <cstdint>
#include <cstddef>

// ---------------------------------------------------------------------------
// CapsNet forward. Round 10:
//  - conv2m: SINGLE-barrier counted-vmcnt pipeline. R9's two-barrier phase
//    shape kept sync overhead at 328 barriers (the R6->R9 regression tracks
//    barrier count, not drains/conflicts). With 3 buffers and stage-distance
//    1, one barrier per sub-round is race-free:
//      iter sr: stage((sr+1)%3) -> vmcnt(nld) -> s_barrier -> compute(sr%3)
//    stage(sr+1) writes the buffer last read in iter sr-2; the iter-(sr-1)
//    barrier separates (max wave skew = 1 barrier). Wait precedes barrier so
//    post-barrier the buffer is complete for all waves. 164 barriers total,
//    counted waits (A-waves vmcnt(3), W-waves vmcnt(4)), vmcnt(0) only at
//    the final sub-round.
//  - 43KB LDS (3 x 14KB), 3 blocks/CU, grid (96,2,4)=768 balanced.
//  - round-8 conflict-free interleaved-line swizzle kept (verified 0
//    conflicts): line L holds rows 2L,2L+1, chunk p=(parity*4+icchunk)^(L&7);
//    linear global_load_lds dest, permutation folded into global src addr.
//  - s_setprio(1) around MFMA cluster kept. Everything else unchanged.
// Workspace (bytes):
//   h    [0, 52428800)           bf16 [b][pix400][ic256]
//   wt   [52428800, 63045632)    bf16 [k81][oc256][ic256]
//   pp0  [63045632, 72482816)    f32  partial (half0,seg0) [b][oc][36]
//   pp1  [72482816, 81920000)    f32  partial (half0,seg1)
//   U    [81920000, 91357184)    f32  [b][ik]
//   pp3  [91357184, 100794368)   f32  partial (half1,seg1)  (aliases dwT2+part head)
//   dwT2 [91357184, 97255424)    f32  [co160][ik9216]       (written after squash1)
//   part [97255424, 102498304)   f32  [kc32][b256][co160]   (written by gemm1)
//   csm  [102498304,102544384)   f32  [i][c]
//   bij  [102544384,102590464)   f32  [i][c]
//   outT [102590464,102754304)   f32  [co160][b256]
//   outw [102754304,102918144)   f32  [b][co160]
//   pp2  [102918144,112355328)   f32  partial (half1,seg0)  (aliases UT)
//   UT   [102918144,112355328)   f32  [ik9216][b256]        (written after squash1)
// ---------------------------------------------------------------------------

typedef __attribute__((ext_vector_type(8))) short short8;
typedef __attribute__((ext_vector_type(4))) float f32x4;

#define PHALF 2359296

__device__ __forceinline__ unsigned short f2bf_rn(float x) {
    unsigned u = __float_as_uint(x);
    unsigned r = (u + 0x7fffu + ((u >> 16) & 1u)) >> 16;
    return (unsigned short)r;
}

// prim_w (256 oc, 256 ic, 81) fp32 -> wt[k][oc][ic] bf16
__global__ void k_makew(const float* __restrict__ w2,
                        unsigned short* __restrict__ wt) {
    __shared__ float lw[20736];   // [8 oc][32 ic][81 k]
    int ocg = blockIdx.x, icg = blockIdx.y, t = threadIdx.x;
    for (int idx = t; idx < 20736; idx += 256) {
        int row = idx / 81, k = idx % 81;
        int oc_l = row >> 5, ic_l = row & 31;
        lw[idx] = w2[((size_t)(ocg * 8 + oc_l) * 256 + icg * 32 + ic_l) * 81 + k];
    }
    __syncthreads();
    for (int idx = t; idx < 2592; idx += 256) {   // 81 k * 8 oc * 4 slots
        int k = idx >> 5;
        int r = idx & 31;
        int oc_l = r >> 2, sl = r & 3;
        unsigned short hi8[8];
        #pragma unroll
        for (int j = 0; j < 8; j++)
            hi8[j] = f2bf_rn(lw[(oc_l * 32 + sl * 8 + j) * 81 + k]);
        size_t o = ((size_t)(k * 256 + ocg * 8 + oc_l)) * 256 + icg * 32 + sl * 8;
        *(uint4*)&wt[o] = *(uint4*)hi8;
    }
}

__global__ void k_conv1(const float* __restrict__ x, const float* __restrict__ cw,
                        const float* __restrict__ cb,
                        unsigned short* __restrict__ h) {
    // grid (256 b, 8 ocg), block 256
    __shared__ float img[784];
    __shared__ float wsm[32 * 81];
    int b = blockIdx.x, ocg = blockIdx.y, t = threadIdx.x;
    for (int idx = t; idx < 784; idx += 256) img[idx] = x[b * 784 + idx];
    for (int idx = t; idx < 2592; idx += 256) wsm[idx] = cw[ocg * 2592 + idx];
    __syncthreads();
    int oc_l = t & 31, g = t >> 5;
    int oc = ocg * 32 + oc_l;
    float bias = cb[oc];
    const float* wp = &wsm[oc_l * 81];
    for (int q = g; q < 100; q += 8) {
        int py = q / 5, qx = (q % 5) * 4;
        float a0 = bias, a1 = bias, a2 = bias, a3 = bias;
        #pragma unroll
        for (int ky = 0; ky < 9; ky++) {
            const float* ir = &img[(py + ky) * 28 + qx];
            float r[12];
            #pragma unroll
            for (int j = 0; j < 12; j++) r[j] = ir[j];
            #pragma unroll
            for (int kx = 0; kx < 9; kx++) {
                float w = wp[ky * 9 + kx];
                a0 += r[kx] * w; a1 += r[kx + 1] * w;
                a2 += r[kx + 2] * w; a3 += r[kx + 3] * w;
            }
        }
        float v[4] = { fmaxf(a0, 0.f), fmaxf(a1, 0.f), fmaxf(a2, 0.f), fmaxf(a3, 0.f) };
        size_t base = ((size_t)b * 400 + py * 20 + qx) * 256 + oc;
        #pragma unroll
        for (int j = 0; j < 4; j++)
            h[base + (size_t)j * 256] = f2bf_rn(v[j]);
    }
}

// Implicit-GEMM bf16 MFMA conv2.
// grid (96 mb, 2 nb, 4 zz) = 768 blocks (3/CU balanced), block 256 (4 waves).
// zz = half*2 + seg. 32-ic sub-rounds; 3 x 7168-short LDS buffers.
// Pipeline: stage(sr+1) -> vmcnt(nld) -> s_barrier -> compute(sr). One
// barrier per sub-round (see header).
__global__ __launch_bounds__(256, 4) void k_conv2m(
    const unsigned short* __restrict__ h,
    const unsigned short* __restrict__ wt,
    float* __restrict__ p0, float* __restrict__ p1,
    float* __restrict__ p2, float* __restrict__ p3)
{
    __shared__ unsigned short smem[21504];   // 3 x 7168 shorts (43008 B)
    const int t = threadIdx.x;
    const int w = t >> 6, l = t & 63;
    const int mb = blockIdx.x, nb = blockIdx.y, zz = blockIdx.z;
    const int half = zz >> 1, seg = zz & 1;

    // staging: w0 A lines 0-23, w1 A lines 24-47, w2 W lines 0-31, w3 W 32-63
    const unsigned short* src;
    int nld, sbase;              // sbase in shorts within buffer
    unsigned rowbase[4];
    const bool isA = (w < 2);
    if (isA) {
        src = h; nld = 3; sbase = w * 1536;
        #pragma unroll
        for (int ld = 0; ld < 3; ld++) {
            int L = w * 24 + ld * 8 + (l >> 3);   // A line 0..47
            int p = l & 7;
            int tt = p ^ (L & 7);
            int s = tt >> 2, qc = tt & 3;
            int row = L * 2 + s;                  // pixel local 0..95
            int P = mb * 96 + row;
            int b = P / 36, o = P % 36;
            int oy = o / 6, ox = o % 6;
            rowbase[ld] = (unsigned)((b * 400 + oy * 40 + ox * 2) * 256 + half * 128 + qc * 8);
        }
    } else {
        src = wt; nld = 4; sbase = 3072 + (w - 2) * 2048;
        #pragma unroll
        for (int ld = 0; ld < 4; ld++) {
            int L = (w - 2) * 32 + ld * 8 + (l >> 3);  // W line local 0..63
            int p = l & 7;
            int tt = p ^ (L & 7);
            int s = tt >> 2, qc = tt & 3;
            int oc = L * 2 + s;                   // oc local 0..127
            rowbase[ld] = (unsigned)((nb * 128 + oc) * 256 + half * 128 + qc * 8);
        }
    }

    // compute setup: waves 2x2, wave tile 48 pix x 64 oc
    const int wm = w & 1, wn = w >> 1;
    const int lane16 = l & 15, q = l >> 4;   // q = 8-ic chunk within 32-ic

    f32x4 acc[3][4] = {};

    const int pos0 = seg ? 41 : 0;
    const int npos = seg ? 40 : 41;
    const int NR = npos * 4;      // 32-ic sub-rounds (160 or 164)

    auto kofs_of = [&](int sr) -> unsigned {
        int pos = pos0 + (sr >> 2), q32 = sr & 3;
        if (isA) {
            int ky = pos / 9, kx = pos - ky * 9;
            return (unsigned)((ky * 20 + kx) * 256 + q32 * 32);
        }
        return (unsigned)(pos * 65536 + q32 * 32);
    };
    auto stage = [&](int bf, unsigned kofs) {
        unsigned short* dst = smem + bf * 7168 + sbase;
        for (int ld = 0; ld < nld; ld++) {
            __builtin_amdgcn_global_load_lds(
                (const __attribute__((address_space(1))) unsigned int*)(const void*)(src + rowbase[ld] + kofs),
                (__attribute__((address_space(3))) unsigned int*)(void*)(dst + ld * 512),
                16, 0, 0);
        }
    };
    auto compute = [&](int bf) {
        const unsigned short* bufp = smem + bf * 7168;
        short8 a[3], b[4];
        #pragma unroll
        for (int mt = 0; mt < 3; mt++) {
            int r = wm * 48 + mt * 16 + lane16;
            int L = r >> 1;
            int p = (((r & 1) << 2) + q) ^ (L & 7);
            a[mt] = *(const short8*)(bufp + L * 64 + p * 8);
        }
        #pragma unroll
        for (int nt = 0; nt < 4; nt++) {
            int r = wn * 64 + nt * 16 + lane16;
            int L = r >> 1;
            int p = (((r & 1) << 2) + q) ^ (L & 7);
            b[nt] = *(const short8*)(bufp + 3072 + L * 64 + p * 8);
        }
        __builtin_amdgcn_s_setprio(1);
        #pragma unroll
        for (int mt = 0; mt < 3; mt++)
            #pragma unroll
            for (int nt = 0; nt < 4; nt++)
                acc[mt][nt] = __builtin_amdgcn_mfma_f32_16x16x32_bf16(a[mt], b[nt], acc[mt][nt], 0, 0, 0);
        __builtin_amdgcn_s_setprio(0);
    };

    #define BARRIER() asm volatile("s_barrier" ::: "memory")
    #define WAIT_NLD() do { if (isA) asm volatile("s_waitcnt vmcnt(3)" ::: "memory"); \
                            else     asm volatile("s_waitcnt vmcnt(4)" ::: "memory"); } while (0)
    #define WAIT_0()   asm volatile("s_waitcnt vmcnt(0)" ::: "memory")

    // prologue: stage sub-round 0 into buffer 0
    stage(0, kofs_of(0));

    // main loop: one barrier per sub-round
    int bc = 0;   // buffer holding sub-round sr
    int st = 1;   // buffer for sub-round sr+1
    for (int sr = 0; sr < NR - 1; ++sr) {
        stage(st, kofs_of(sr + 1));   // writes buf last read in iter sr-2
                                      // (barrier of iter sr-1 separates)
        WAIT_NLD();                   // own stage(sr) loads complete
        BARRIER();                    // all waves: buf bc fully populated
        compute(bc);
        bc = (bc == 2) ? 0 : bc + 1;
        st = (st == 2) ? 0 : st + 1;
    }
    // final sub-round
    WAIT_0();
    BARRIER();
    compute(bc);

    #undef BARRIER
    #undef WAIT_NLD
    #undef WAIT_0

    // epilogue: D row = q*4+reg (pixel), col = lane16 (oc)
    #pragma unroll
    for (int mt = 0; mt < 3; mt++) {
        int pixG = mb * 96 + wm * 48 + mt * 16 + q * 4;
        int b = pixG / 36, p36 = pixG % 36;
        #pragma unroll
        for (int nt = 0; nt < 4; nt++) {
            int oc = nb * 128 + wn * 64 + nt * 16 + lane16;
            float* pout = (zz == 0) ? p0 : (zz == 1) ? p1 : (zz == 2) ? p2 : p3;
            *(f32x4*)&pout[((size_t)(b * 256 + oc)) * 36 + p36] = acc[mt][nt];
        }
    }
}

__global__ void k_squash1(const float* __restrict__ q0, const float* __restrict__ q1,
                          const float* __restrict__ q2, const float* __restrict__ q3,
                          const float* __restrict__ prim_b, float* __restrict__ U) {
    // grid 2048 (b*8+cap), block 256
    __shared__ float red[4];
    int b = blockIdx.x >> 3, cap = blockIdx.x & 7;
    int t = threadIdx.x;
    size_t base = ((size_t)b * 256 + cap * 32) * 36;
    const float* pa = q0 + base;
    const float* pb = q1 + base;
    const float* pc = q2 + base;
    const float* pd = q3 + base;
    float v[5];
    float ss = 0.f;
    #pragma unroll
    for (int j = 0; j < 5; j++) {
        int idx = t + j * 256;
        if (idx < 1152) {
            int ch_l = idx / 36;
            float val = pa[idx] + pb[idx] + pc[idx] + pd[idx] + prim_b[cap * 32 + ch_l];
            v[j] = val; ss += val * val;
        } else v[j] = 0.f;
    }
    for (int off = 32; off; off >>= 1) ss += __shfl_down(ss, off);
    if ((t & 63) == 0) red[t >> 6] = ss;
    __syncthreads();
    float n2 = red[0] + red[1] + red[2] + red[3];
    float f = (n2 / (1.0f + n2)) / (sqrtf(n2) + 1e-10f);
    #pragma unroll
    for (int j = 0; j < 5; j++) {
        int idx = t + j * 256;
        if (idx < 1152) U[(size_t)b * 9216 + idx * 8 + cap] = v[j] * f;
    }
}

// dw (i,c,o,k) -> dwT2[co160][ik9216]
__global__ void k_dwt2(const float* __restrict__ dw, float* __restrict__ dwT2) {
    int co = blockIdx.x, t = threadIdx.x;
    int c = co >> 4, o = co & 15;
    const float* base = dw + c * 128 + o * 8;
    float* out = dwT2 + (size_t)co * 9216;
    for (int idx = t; idx < 9216; idx += 256) {
        int i = idx >> 3, k = idx & 7;
        out[idx] = base[(size_t)i * 1280 + k];
    }
}

// U[b][ik] -> UT[ik][b], 64x64 tiles
__global__ void k_ut(const float* __restrict__ U, float* __restrict__ UT) {
    __shared__ float tl[64][65];
    int ikb = blockIdx.x, bb = blockIdx.y, t = threadIdx.x;
    for (int idx = t; idx < 1024; idx += 256) {
        int row = idx >> 4, c4 = idx & 15;
        float4 v = *(const float4*)&U[(size_t)(bb * 64 + row) * 9216 + ikb * 64 + c4 * 4];
        tl[c4 * 4 + 0][row] = v.x;
        tl[c4 * 4 + 1][row] = v.y;
        tl[c4 * 4 + 2][row] = v.z;
        tl[c4 * 4 + 3][row] = v.w;
    }
    __syncthreads();
    for (int idx = t; idx < 1024; idx += 256) {
        int row = idx >> 4, c4 = idx & 15;
        float4 v = make_float4(tl[row][c4 * 4 + 0], tl[row][c4 * 4 + 1],
                               tl[row][c4 * 4 + 2], tl[row][c4 * 4 + 3]);
        *(float4*)&UT[(size_t)(ikb * 64 + row) * 256 + bb * 64 + c4 * 4] = v;
    }
}

__global__ void k_softmax(const float* __restrict__ bij, float* __restrict__ csm) {
    __shared__ float red[4];
    int c = blockIdx.x, t = threadIdx.x;
    float vals[5];
    float mx = -1e30f;
    #pragma unroll
    for (int j = 0; j < 5; j++) {
        int i = t + j * 256;
        vals[j] = (i < 1152) ? bij[i * 10 + c] : -1e30f;
        mx = fmaxf(mx, vals[j]);
    }
    for (int off = 32; off; off >>= 1) mx = fmaxf(mx, __shfl_down(mx, off));
    if ((t & 63) == 0) red[t >> 6] = mx;
    __syncthreads();
    mx = fmaxf(fmaxf(red[0], red[1]), fmaxf(red[2], red[3]));
    __syncthreads();
    float s = 0.f;
    #pragma unroll
    for (int j = 0; j < 5; j++) {
        int i = t + j * 256;
        vals[j] = (i < 1152) ? expf(vals[j] - mx) : 0.f;
        s += vals[j];
    }
    for (int off = 32; off; off >>= 1) s += __shfl_down(s, off);
    if ((t & 63) == 0) red[t >> 6] = s;
    __syncthreads();
    s = red[0] + red[1] + red[2] + red[3];
    float inv = 1.0f / s;
    #pragma unroll
    for (int j = 0; j < 5; j++) {
        int i = t + j * 256;
        if (i < 1152) csm[i * 10 + c] = vals[j] * inv;
    }
}

// s_j partial GEMM. A-panel register cache + b128 swizzled WsT reads.
// grid (8 mb, 32 kc), block 256. part[kc][row][160].
__global__ __launch_bounds__(256) void k_gemm1(const float* __restrict__ U,
                                               const float* __restrict__ dwT2,
                                               const float* __restrict__ csm,
                                               float* __restrict__ part,
                                               int uniform) {
    __shared__ float Us[32 * 36];     // [row][kk 32 +pad]
    __shared__ float WsT[5120];       // [co160][chunk8 swizzled][4]
    __shared__ float cl[360];
    int mb = blockIdx.x, kc = blockIdx.y, t = threadIdx.x;
    int tc = t & 15, tb = t >> 4;
    if (!uniform)
        for (int idx = t; idx < 360; idx += 256) cl[idx] = csm[kc * 360 + idx];
    const float uscale = 1.0f / 1152.0f;
    float acc[2][10] = {};
    for (int ks = 0; ks < 9; ks++) {
        __syncthreads();
        {   // stage Us: 32 rows x 32 kk
            int bb = t >> 3, k4 = t & 7;
            *(float4*)&Us[bb * 36 + k4 * 4] =
                *(const float4*)&U[(size_t)(mb * 32 + bb) * 9216 + kc * 288 + ks * 32 + k4 * 4];
        }
        // stage WsT lane-linear with chunk swizzle; fold c_ij
        #pragma unroll
        for (int pass = 0; pass < 5; pass++) {
            int s = t + pass * 256;
            int co = s >> 3, p = s & 7;
            int kq = p ^ (co & 7);
            int ikl = ks * 32 + kq * 4;
            float4 v = *(const float4*)&dwT2[(size_t)co * 9216 + kc * 288 + ikl];
            float sc = uniform ? uscale : cl[(ikl >> 3) * 10 + (co >> 4)];
            v.x *= sc; v.y *= sc; v.z *= sc; v.w *= sc;
            *(float4*)&WsT[s * 4] = v;
        }
        __syncthreads();
        // A-panel into registers: 2 rows x 32 kk
        float a0[32], a1[32];
        #pragma unroll
        for (int kq = 0; kq < 8; kq++) {
            float4 v0 = *(const float4*)&Us[(tb * 2) * 36 + kq * 4];
            float4 v1 = *(const float4*)&Us[(tb * 2 + 1) * 36 + kq * 4];
            a0[kq * 4 + 0] = v0.x; a0[kq * 4 + 1] = v0.y; a0[kq * 4 + 2] = v0.z; a0[kq * 4 + 3] = v0.w;
            a1[kq * 4 + 0] = v1.x; a1[kq * 4 + 1] = v1.y; a1[kq * 4 + 2] = v1.z; a1[kq * 4 + 3] = v1.w;
        }
        #pragma unroll
        for (int j = 0; j < 10; j++) {
            int co = tc + 16 * j;
            int cx = co & 7, cbase = co * 32;
            #pragma unroll
            for (int kq = 0; kq < 8; kq++) {
                float4 wv = *(const float4*)&WsT[cbase + ((kq ^ cx) << 2)];
                acc[0][j] += a0[kq * 4 + 0] * wv.x; acc[0][j] += a0[kq * 4 + 1] * wv.y;
                acc[0][j] += a0[kq * 4 + 2] * wv.z; acc[0][j] += a0[kq * 4 + 3] * wv.w;
                acc[1][j] += a1[kq * 4 + 0] * wv.x; acc[1][j] += a1[kq * 4 + 1] * wv.y;
                acc[1][j] += a1[kq * 4 + 2] * wv.z; acc[1][j] += a1[kq * 4 + 3] * wv.w;
            }
        }
    }
    #pragma unroll
    for (int r = 0; r < 2; r++)
        #pragma unroll
        for (int j = 0; j < 10; j++)
            part[(size_t)kc * 40960 + (mb * 32 + tb * 2 + r) * 160 + tc + 16 * j] = acc[r][j];
}

__global__ void k_redsq(const float* __restrict__ part, float* __restrict__ out,
                        float* __restrict__ outT, int writeT) {
    __shared__ float sl[160];
    __shared__ float n2s[16];
    int b = blockIdx.x, t = threadIdx.x;
    float s = 0.f;
    if (t < 160) {
        for (int kc = 0; kc < 32; kc++) s += part[(size_t)kc * 40960 + b * 160 + t];
        sl[t] = s;
    }
    __syncthreads();
    if (t < 16) {
        float n2 = 0.f;
        #pragma unroll
        for (int c = 0; c < 10; c++) { float v = sl[c * 16 + t]; n2 += v * v; }
        n2s[t] = n2;
    }
    __syncthreads();
    if (t < 160) {
        float n2 = n2s[t & 15];
        float f = (n2 / (1.0f + n2)) / (sqrtf(n2) + 1e-10f);
        float r = s * f;
        out[(size_t)b * 160 + t] = r;
        if (writeT) outT[(size_t)t * 256 + b] = r;
    }
}

// Fused agreement via UT/outT: M2 rows in-register (b128 swizzled LDS reads),
// contracted with dw, bij updated. grid 288 (4 i's each), block 256.
__global__ __launch_bounds__(256) void k_g2uv(const float* __restrict__ UT,
                                              const float* __restrict__ outTg,
                                              const float* __restrict__ dw,
                                              float* __restrict__ bij) {
    __shared__ float UsT[1024];    // [m32][chunk8 swizzled][4]
    __shared__ float OsT[5120];    // [co160][chunk8 swizzled][4]
    __shared__ float dwl[5120];
    __shared__ float sb[320];
    int blk = blockIdx.x, t = threadIdx.x;
    int tc = t & 15, tm = t >> 4;
    for (int idx = t; idx < 5120; idx += 256)
        dwl[idx] = dw[(size_t)blk * 5120 + idx];
    float acc[2][10] = {};
    for (int bs = 0; bs < 256; bs += 32) {
        __syncthreads();
        {   // stage UsT lane-linear, swizzled
            int m = t >> 3, p = t & 7;
            int kq = p ^ (m & 7);
            *(float4*)&UsT[t * 4] =
                *(const float4*)&UT[(size_t)(blk * 32 + m) * 256 + bs + kq * 4];
        }
        #pragma unroll
        for (int pass = 0; pass < 5; pass++) {
            int s = t + pass * 256;
            int co = s >> 3, p = s & 7;
            int kq = p ^ (co & 7);
            *(float4*)&OsT[s * 4] =
                *(const float4*)&outTg[(size_t)co * 256 + bs + kq * 4];
        }
        __syncthreads();
        float a0[32], a1[32];
        int m0 = tm * 2, m1 = tm * 2 + 1;
        #pragma unroll
        for (int kq = 0; kq < 8; kq++) {
            float4 v0 = *(const float4*)&UsT[m0 * 32 + ((kq ^ (m0 & 7)) << 2)];
            float4 v1 = *(const float4*)&UsT[m1 * 32 + ((kq ^ (m1 & 7)) << 2)];
            a0[kq * 4 + 0] = v0.x; a0[kq * 4 + 1] = v0.y; a0[kq * 4 + 2] = v0.z; a0[kq * 4 + 3] = v0.w;
            a1[kq * 4 + 0] = v1.x; a1[kq * 4 + 1] = v1.y; a1[kq * 4 + 2] = v1.z; a1[kq * 4 + 3] = v1.w;
        }
        #pragma unroll
        for (int j = 0; j < 10; j++) {
            int co = tc + 16 * j;
            int cx = co & 7, cbase = co * 32;
            #pragma unroll
            for (int kq = 0; kq < 8; kq++) {
                float4 wv = *(const float4*)&OsT[cbase + ((kq ^ cx) << 2)];
                acc[0][j] += a0[kq * 4 + 0] * wv.x; acc[0][j] += a0[kq * 4 + 1] * wv.y;
                acc[0][j] += a0[kq * 4 + 2] * wv.z; acc[0][j] += a0[kq * 4 + 3] * wv.w;
                acc[1][j] += a1[kq * 4 + 0] * wv.x; acc[1][j] += a1[kq * 4 + 1] * wv.y;
                acc[1][j] += a1[kq * 4 + 2] * wv.z; acc[1][j] += a1[kq * 4 + 3] * wv.w;
            }
        }
    }
    // contract with dw over o (=tc) per (ik_local, c)
    #pragma unroll
    for (int r = 0; r < 2; r++) {
        int ik_l = tm * 2 + r;
        int i_l = ik_l >> 3, k = ik_l & 7;
        #pragma unroll
        for (int j = 0; j < 10; j++) {
            float v = acc[r][j] * dwl[i_l * 1280 + (j * 16 + tc) * 8 + k];
            v += __shfl_down(v, 8, 16);
            v += __shfl_down(v, 4, 16);
            v += __shfl_down(v, 2, 16);
            v += __shfl_down(v, 1, 16);
            if (tc == 0) sb[ik_l * 10 + j] = v;
        }
    }
    __syncthreads();
    if (t < 40) {
        int i_l = t / 10, c = t % 10;
        float s = 0.f;
        #pragma unroll
        for (int kk = 0; kk < 8; kk++) s += sb[(i_l * 8 + kk) * 10 + c];
        size_t o = (size_t)(blk * 4 + i_l) * 10 + c;
        bij[o] += s * (1.0f / 256.0f);
    }
}

extern "C" void kernel_launch(void* const* d_in, const int* in_sizes, int n_in,
                              void* d_out, int out_size, void* d_ws, size_t ws_size,
                              hipStream_t stream) {
    const float* x      = (const float*)d_in[0];
    const float* conv_w = (const float*)d_in[1];
    const float* conv_b = (const float*)d_in[2];
    const float* prim_w = (const float*)d_in[3];
    const float* prim_b = (const float*)d_in[4];
    const float* dw     = (const float*)d_in[5];

    char* wsb = (char*)d_ws;
    unsigned short* h  = (unsigned short*)(wsb);
    unsigned short* wt = (unsigned short*)(wsb + 52428800);
    float* pp0  = (float*)(wsb + 63045632);
    float* pp1  = (float*)(wsb + 72482816);
    float* U    = (float*)(wsb + 81920000);
    float* dwT2 = (float*)(wsb + 91357184);
    float* pp3  = (float*)(wsb + 91357184);    // aliases dwT2 + part head
    float* part = (float*)(wsb + 97255424);
    float* csm  = (float*)(wsb + 102498304);
    float* bij  = (float*)(wsb + 102544384);
    float* outT = (float*)(wsb + 102590464);
    float* outw = (float*)(wsb + 102754304);
    float* UT   = (float*)(wsb + 102918144);
    float* pp2  = (float*)(wsb + 102918144);   // aliases UT

    k_makew<<<dim3(32, 8), 256, 0, stream>>>(prim_w, wt);
    k_conv1<<<dim3(256, 8), 256, 0, stream>>>(x, conv_w, conv_b, h);
    k_conv2m<<<dim3(96, 2, 4), 256, 0, stream>>>(h, wt, pp0, pp1, pp2, pp3);
    k_squash1<<<2048, 256, 0, stream>>>(pp0, pp1, pp2, pp3, prim_b, U);
    // dwT2 / UT are written only after squash1 consumed the pp partials
    k_dwt2<<<160, 256, 0, stream>>>(dw, dwT2);
    k_ut<<<dim3(144, 4), 256, 0, stream>>>(U, UT);
    hipMemsetAsync(bij, 0, 11520 * sizeof(float), stream);

    // iter 0 (b_ij = 0 -> uniform c)
    k_gemm1<<<dim3(8, 32), 256, 0, stream>>>(U, dwT2, csm, part, 1);
    k_redsq<<<256, 256, 0, stream>>>(part, outw, outT, 1);
    k_g2uv<<<288, 256, 0, stream>>>(UT, outT, dw, bij);
    k_softmax<<<10, 256, 0, stream>>>(bij, csm);
    // iter 1
    k_gemm1<<<dim3(8, 32), 256, 0, stream>>>(U, dwT2, csm, part, 0);
    k_redsq<<<256, 256, 0, stream>>>(part, outw, outT, 1);
    k_g2uv<<<288, 256, 0, stream>>>(UT, outT, dw, bij);
    k_softmax<<<10, 256, 0, stream>>>(bij, csm);
    // iter 2
    k_gemm1<<<dim3(8, 32), 256, 0, stream>>>(U, dwT2, csm, part, 0);
    k_redsq<<<256, 256, 0, stream>>>(part, (float*)d_out, outT, 0);
}

// Round 6
// 478.956 us; speedup vs baseline: 1.0536x; 1.0536x over previous
//
#include <hip/hip_runtime.h>
#include <cstdint>
#include <cstddef>

// ---------------------------------------------------------------------------
// CapsNet forward. Round 11:
//  - conv2m REVERTED to the round-6 schedule (measured 137us; all four
//    pipelined variants R7-R10 measured 150-153 -> R6 is the local optimum
//    of this structure; conflicts/drains/barrier-count all exonerated).
//  - Launch-count reduction (testing the ~8us/launch gap hypothesis:
//    sum-of-kernel models ~350us vs measured 504):
//    * k_pre = conv1 + makew fused (heterogeneous blocks, independent work;
//      makew restructured per-oc so LDS union = 13.5KB).
//    * k_ut DELETED: g2uv transposes its 32x32 U tile in-LDS per bs-chunk
//      (same UsT layout as before -> compute loop untouched). Saves a
//      launch + 9.4MB HBM write + read.
//    * k_dwt2 stays separate (dwT2 region aliases pp3; must run after
//      squash1). 19 -> 16 launches.
// Workspace (bytes):
//   h    [0, 52428800)           bf16 [b][pix400][ic256]
//   wt   [52428800, 63045632)    bf16 [k81][oc256][ic256]
//   pp0  [63045632, 72482816)    f32  partial (half0,seg0) [b][oc][36]
//   pp1  [72482816, 81920000)    f32  partial (half0,seg1)
//   U    [81920000, 91357184)    f32  [b][ik]
//   pp3  [91357184, 100794368)   f32  partial (half1,seg1)  (aliases dwT2+part head)
//   dwT2 [91357184, 97255424)    f32  [co160][ik9216]       (written after squash1)
//   part [97255424, 102498304)   f32  [kc32][b256][co160]   (written by gemm1)
//   csm  [102498304,102544384)   f32  [i][c]
//   bij  [102544384,102590464)   f32  [i][c]
//   outT [102590464,102754304)   f32  [co160][b256]
//   outw [102754304,102918144)   f32  [b][co160]
//   pp2  [102918144,112355328)   f32  partial (half1,seg0)  (former UT region)
// ---------------------------------------------------------------------------

typedef __attribute__((ext_vector_type(8))) short short8;
typedef __attribute__((ext_vector_type(4))) float f32x4;

#define PHALF 2359296

__device__ __forceinline__ unsigned short f2bf_rn(float x) {
    unsigned u = __float_as_uint(x);
    unsigned r = (u + 0x7fffu + ((u >> 16) & 1u)) >> 16;
    return (unsigned short)r;
}

// Fused preprocessing: blocks 0..2047 conv1, blocks 2048..4095 makew.
// conv1: 1->256 k9 s1 + ReLU, h[b][pix][ic] bf16.
// makew: prim_w (256 oc, 256 ic, 81) fp32 -> wt[k][oc][ic] bf16, per-oc blocks.
__global__ void k_pre(const float* __restrict__ x, const float* __restrict__ cw,
                      const float* __restrict__ cb, const float* __restrict__ w2,
                      unsigned short* __restrict__ h, unsigned short* __restrict__ wt) {
    __shared__ float sh[3376];
    int blk = blockIdx.x, t = threadIdx.x;
    if (blk < 2048) {
        // conv1: b = blk>>3, ocg = blk&7
        float* img = sh;            // 784
        float* wsm = sh + 784;      // 2592
        int b = blk >> 3, ocg = blk & 7;
        for (int idx = t; idx < 784; idx += 256) img[idx] = x[b * 784 + idx];
        for (int idx = t; idx < 2592; idx += 256) wsm[idx] = cw[ocg * 2592 + idx];
        __syncthreads();
        int oc_l = t & 31, g = t >> 5;
        int oc = ocg * 32 + oc_l;
        float bias = cb[oc];
        const float* wp = &wsm[oc_l * 81];
        for (int q = g; q < 100; q += 8) {
            int py = q / 5, qx = (q % 5) * 4;
            float a0 = bias, a1 = bias, a2 = bias, a3 = bias;
            #pragma unroll
            for (int ky = 0; ky < 9; ky++) {
                const float* ir = &img[(py + ky) * 28 + qx];
                float r[12];
                #pragma unroll
                for (int j = 0; j < 12; j++) r[j] = ir[j];
                #pragma unroll
                for (int kx = 0; kx < 9; kx++) {
                    float w = wp[ky * 9 + kx];
                    a0 += r[kx] * w; a1 += r[kx + 1] * w;
                    a2 += r[kx + 2] * w; a3 += r[kx + 3] * w;
                }
            }
            float v[4] = { fmaxf(a0, 0.f), fmaxf(a1, 0.f), fmaxf(a2, 0.f), fmaxf(a3, 0.f) };
            size_t base = ((size_t)b * 400 + py * 20 + qx) * 256 + oc;
            #pragma unroll
            for (int j = 0; j < 4; j++)
                h[base + (size_t)j * 256] = f2bf_rn(v[j]);
        }
    } else {
        // makew: oc = (blk-2048)>>3, icg = (blk-2048)&7
        int m2 = blk - 2048;
        int oc = m2 >> 3, icg = m2 & 7;
        float* lw2 = sh;            // 2592 = [32 ic][81 k]
        for (int idx = t; idx < 2592; idx += 256) {
            int ic_l = idx / 81, k = idx % 81;
            lw2[idx] = w2[((size_t)oc * 256 + icg * 32 + ic_l) * 81 + k];
        }
        __syncthreads();
        for (int idx = t; idx < 324; idx += 256) {   // 81 k * 4 slots
            int k = idx >> 2, sl = idx & 3;
            unsigned short hi8[8];
            #pragma unroll
            for (int j = 0; j < 8; j++)
                hi8[j] = f2bf_rn(lw2[(sl * 8 + j) * 81 + k]);
            size_t o = ((size_t)(k * 256 + oc)) * 256 + icg * 32 + sl * 8;
            *(uint4*)&wt[o] = *(uint4*)hi8;
        }
    }
}

// Implicit-GEMM bf16 MFMA conv2 — ROUND-6 schedule (measured 137us).
// grid (96 mb, 2 nb, 4 zz) = 768 blocks (3/CU balanced), block 256 (4 waves).
// zz = half*2 + seg. Each round stages a 64-ic chunk: A 96pix x 64ic (12KB)
// + W 128oc x 64ic (16KB) = 28KB LDS. Wave tile 48 pix x 64 oc.
__global__ __launch_bounds__(256, 4) void k_conv2m(
    const unsigned short* __restrict__ h,
    const unsigned short* __restrict__ wt,
    float* __restrict__ p0, float* __restrict__ p1,
    float* __restrict__ p2, float* __restrict__ p3)
{
    // A: rows pix*64 at 0; W: rows oc*64 at 6144 (shorts)
    __shared__ unsigned short smem[14336];   // 28672 B
    const int t = threadIdx.x;
    const int w = t >> 6, l = t & 63;
    const int mb = blockIdx.x, nb = blockIdx.y, zz = blockIdx.z;
    const int half = zz >> 1, seg = zz & 1;

    // staging roles: w0 A rows 0-47, w1 A rows 48-95, w2 W oc 0-63, w3 W 64-127
    const unsigned short* src;
    int nld, sbase;
    unsigned rowbase[8];
    if (w < 2) {
        src = h; nld = 6; sbase = w * 3072;
        #pragma unroll
        for (int ld = 0; ld < 6; ld++) {
            int row = w * 48 + ld * 8 + (l >> 3);      // pixel local 0..95
            int c = l & 7;
            int g = c ^ (row & 7);
            int P = mb * 96 + row;
            int b = P / 36, o = P % 36;
            int oy = o / 6, ox = o % 6;
            rowbase[ld] = (unsigned)((b * 400 + oy * 40 + ox * 2) * 256 + half * 128 + g * 8);
        }
    } else {
        src = wt; nld = 8; sbase = 6144 + (w - 2) * 4096;
        #pragma unroll
        for (int ld = 0; ld < 8; ld++) {
            int oc = (w - 2) * 64 + ld * 8 + (l >> 3); // oc local 0..127
            int c = l & 7;
            int g = c ^ (oc & 7);
            rowbase[ld] = (unsigned)((nb * 128 + oc) * 256 + half * 128 + g * 8);
        }
    }

    // compute setup: waves 2x2, wave tile 48 pix x 64 oc
    const int wm = w & 1, wn = w >> 1;
    const int lane16 = l & 15, q = l >> 4;

    f32x4 acc[3][4] = {};

    const int pos0 = seg ? 41 : 0;
    const int pos1 = seg ? 81 : 41;
    for (int pos = pos0; pos < pos1; ++pos) {
        const int ky = pos / 9, kx = pos - ky * 9;
        const unsigned kbase = (w < 2) ? (unsigned)((ky * 20 + kx) * 256)
                                       : (unsigned)(pos * 65536);
        for (int icc = 0; icc < 2; ++icc) {
            const unsigned kofs = kbase + icc * 64;
            __syncthreads();
            for (int ld = 0; ld < nld; ld++) {
                __builtin_amdgcn_global_load_lds(
                    (const __attribute__((address_space(1))) unsigned int*)(const void*)(src + rowbase[ld] + kofs),
                    (__attribute__((address_space(3))) unsigned int*)(void*)(smem + sbase + ld * 512),
                    16, 0, 0);
            }
            __syncthreads();
            #pragma unroll
            for (int ic2 = 0; ic2 < 2; ic2++) {
                short8 a[3], b[4];
                #pragma unroll
                for (int mt = 0; mt < 3; mt++) {
                    int pixL = wm * 48 + mt * 16 + lane16;
                    int ps = (ic2 * 4 + q) ^ (pixL & 7);
                    a[mt] = *(const short8*)(smem + pixL * 64 + ps * 8);
                }
                #pragma unroll
                for (int nt = 0; nt < 4; nt++) {
                    int ocL = wn * 64 + nt * 16 + lane16;
                    int ps = (ic2 * 4 + q) ^ (ocL & 7);
                    b[nt] = *(const short8*)(smem + 6144 + ocL * 64 + ps * 8);
                }
                #pragma unroll
                for (int mt = 0; mt < 3; mt++)
                    #pragma unroll
                    for (int nt = 0; nt < 4; nt++)
                        acc[mt][nt] = __builtin_amdgcn_mfma_f32_16x16x32_bf16(a[mt], b[nt], acc[mt][nt], 0, 0, 0);
            }
        }
    }

    // epilogue: D row = q*4+reg (pixel), col = lane16 (oc)
    #pragma unroll
    for (int mt = 0; mt < 3; mt++) {
        int pixG = mb * 96 + wm * 48 + mt * 16 + q * 4;
        int b = pixG / 36, p36 = pixG % 36;
        #pragma unroll
        for (int nt = 0; nt < 4; nt++) {
            int oc = nb * 128 + wn * 64 + nt * 16 + lane16;
            float* pout = (zz == 0) ? p0 : (zz == 1) ? p1 : (zz == 2) ? p2 : p3;
            *(f32x4*)&pout[((size_t)(b * 256 + oc)) * 36 + p36] = acc[mt][nt];
        }
    }
}

__global__ void k_squash1(const float* __restrict__ q0, const float* __restrict__ q1,
                          const float* __restrict__ q2, const float* __restrict__ q3,
                          const float* __restrict__ prim_b, float* __restrict__ U) {
    // grid 2048 (b*8+cap), block 256
    __shared__ float red[4];
    int b = blockIdx.x >> 3, cap = blockIdx.x & 7;
    int t = threadIdx.x;
    size_t base = ((size_t)b * 256 + cap * 32) * 36;
    const float* pa = q0 + base;
    const float* pb = q1 + base;
    const float* pc = q2 + base;
    const float* pd = q3 + base;
    float v[5];
    float ss = 0.f;
    #pragma unroll
    for (int j = 0; j < 5; j++) {
        int idx = t + j * 256;
        if (idx < 1152) {
            int ch_l = idx / 36;
            float val = pa[idx] + pb[idx] + pc[idx] + pd[idx] + prim_b[cap * 32 + ch_l];
            v[j] = val; ss += val * val;
        } else v[j] = 0.f;
    }
    for (int off = 32; off; off >>= 1) ss += __shfl_down(ss, off);
    if ((t & 63) == 0) red[t >> 6] = ss;
    __syncthreads();
    float n2 = red[0] + red[1] + red[2] + red[3];
    float f = (n2 / (1.0f + n2)) / (sqrtf(n2) + 1e-10f);
    #pragma unroll
    for (int j = 0; j < 5; j++) {
        int idx = t + j * 256;
        if (idx < 1152) U[(size_t)b * 9216 + idx * 8 + cap] = v[j] * f;
    }
}

// dw (i,c,o,k) -> dwT2[co160][ik9216]  (runs after squash1: region aliases pp3)
__global__ void k_dwt2(const float* __restrict__ dw, float* __restrict__ dwT2) {
    int co = blockIdx.x, t = threadIdx.x;
    int c = co >> 4, o = co & 15;
    const float* base = dw + c * 128 + o * 8;
    float* out = dwT2 + (size_t)co * 9216;
    for (int idx = t; idx < 9216; idx += 256) {
        int i = idx >> 3, k = idx & 7;
        out[idx] = base[(size_t)i * 1280 + k];
    }
}

__global__ void k_softmax(const float* __restrict__ bij, float* __restrict__ csm) {
    __shared__ float red[4];
    int c = blockIdx.x, t = threadIdx.x;
    float vals[5];
    float mx = -1e30f;
    #pragma unroll
    for (int j = 0; j < 5; j++) {
        int i = t + j * 256;
        vals[j] = (i < 1152) ? bij[i * 10 + c] : -1e30f;
        mx = fmaxf(mx, vals[j]);
    }
    for (int off = 32; off; off >>= 1) mx = fmaxf(mx, __shfl_down(mx, off));
    if ((t & 63) == 0) red[t >> 6] = mx;
    __syncthreads();
    mx = fmaxf(fmaxf(red[0], red[1]), fmaxf(red[2], red[3]));
    __syncthreads();
    float s = 0.f;
    #pragma unroll
    for (int j = 0; j < 5; j++) {
        int i = t + j * 256;
        vals[j] = (i < 1152) ? expf(vals[j] - mx) : 0.f;
        s += vals[j];
    }
    for (int off = 32; off; off >>= 1) s += __shfl_down(s, off);
    if ((t & 63) == 0) red[t >> 6] = s;
    __syncthreads();
    s = red[0] + red[1] + red[2] + red[3];
    float inv = 1.0f / s;
    #pragma unroll
    for (int j = 0; j < 5; j++) {
        int i = t + j * 256;
        if (i < 1152) csm[i * 10 + c] = vals[j] * inv;
    }
}

// s_j partial GEMM. A-panel register cache + b128 swizzled WsT reads.
// grid (8 mb, 32 kc), block 256. part[kc][row][160].
__global__ __launch_bounds__(256) void k_gemm1(const float* __restrict__ U,
                                               const float* __restrict__ dwT2,
                                               const float* __restrict__ csm,
                                               float* __restrict__ part,
                                               int uniform) {
    __shared__ float Us[32 * 36];     // [row][kk 32 +pad]
    __shared__ float WsT[5120];       // [co160][chunk8 swizzled][4]
    __shared__ float cl[360];
    int mb = blockIdx.x, kc = blockIdx.y, t = threadIdx.x;
    int tc = t & 15, tb = t >> 4;
    if (!uniform)
        for (int idx = t; idx < 360; idx += 256) cl[idx] = csm[kc * 360 + idx];
    const float uscale = 1.0f / 1152.0f;
    float acc[2][10] = {};
    for (int ks = 0; ks < 9; ks++) {
        __syncthreads();
        {   // stage Us: 32 rows x 32 kk
            int bb = t >> 3, k4 = t & 7;
            *(float4*)&Us[bb * 36 + k4 * 4] =
                *(const float4*)&U[(size_t)(mb * 32 + bb) * 9216 + kc * 288 + ks * 32 + k4 * 4];
        }
        // stage WsT lane-linear with chunk swizzle; fold c_ij
        #pragma unroll
        for (int pass = 0; pass < 5; pass++) {
            int s = t + pass * 256;
            int co = s >> 3, p = s & 7;
            int kq = p ^ (co & 7);
            int ikl = ks * 32 + kq * 4;
            float4 v = *(const float4*)&dwT2[(size_t)co * 9216 + kc * 288 + ikl];
            float sc = uniform ? uscale : cl[(ikl >> 3) * 10 + (co >> 4)];
            v.x *= sc; v.y *= sc; v.z *= sc; v.w *= sc;
            *(float4*)&WsT[s * 4] = v;
        }
        __syncthreads();
        // A-panel into registers: 2 rows x 32 kk
        float a0[32], a1[32];
        #pragma unroll
        for (int kq = 0; kq < 8; kq++) {
            float4 v0 = *(const float4*)&Us[(tb * 2) * 36 + kq * 4];
            float4 v1 = *(const float4*)&Us[(tb * 2 + 1) * 36 + kq * 4];
            a0[kq * 4 + 0] = v0.x; a0[kq * 4 + 1] = v0.y; a0[kq * 4 + 2] = v0.z; a0[kq * 4 + 3] = v0.w;
            a1[kq * 4 + 0] = v1.x; a1[kq * 4 + 1] = v1.y; a1[kq * 4 + 2] = v1.z; a1[kq * 4 + 3] = v1.w;
        }
        #pragma unroll
        for (int j = 0; j < 10; j++) {
            int co = tc + 16 * j;
            int cx = co & 7, cbase = co * 32;
            #pragma unroll
            for (int kq = 0; kq < 8; kq++) {
                float4 wv = *(const float4*)&WsT[cbase + ((kq ^ cx) << 2)];
                acc[0][j] += a0[kq * 4 + 0] * wv.x; acc[0][j] += a0[kq * 4 + 1] * wv.y;
                acc[0][j] += a0[kq * 4 + 2] * wv.z; acc[0][j] += a0[kq * 4 + 3] * wv.w;
                acc[1][j] += a1[kq * 4 + 0] * wv.x; acc[1][j] += a1[kq * 4 + 1] * wv.y;
                acc[1][j] += a1[kq * 4 + 2] * wv.z; acc[1][j] += a1[kq * 4 + 3] * wv.w;
            }
        }
    }
    #pragma unroll
    for (int r = 0; r < 2; r++)
        #pragma unroll
        for (int j = 0; j < 10; j++)
            part[(size_t)kc * 40960 + (mb * 32 + tb * 2 + r) * 160 + tc + 16 * j] = acc[r][j];
}

__global__ void k_redsq(const float* __restrict__ part, float* __restrict__ out,
                        float* __restrict__ outT, int writeT) {
    __shared__ float sl[160];
    __shared__ float n2s[16];
    int b = blockIdx.x, t = threadIdx.x;
    float s = 0.f;
    if (t < 160) {
        for (int kc = 0; kc < 32; kc++) s += part[(size_t)kc * 40960 + b * 160 + t];
        sl[t] = s;
    }
    __syncthreads();
    if (t < 16) {
        float n2 = 0.f;
        #pragma unroll
        for (int c = 0; c < 10; c++) { float v = sl[c * 16 + t]; n2 += v * v; }
        n2s[t] = n2;
    }
    __syncthreads();
    if (t < 160) {
        float n2 = n2s[t & 15];
        float f = (n2 / (1.0f + n2)) / (sqrtf(n2) + 1e-10f);
        float r = s * f;
        out[(size_t)b * 160 + t] = r;
        if (writeT) outT[(size_t)t * 256 + b] = r;
    }
}

// Fused agreement: UT eliminated — per bs-chunk the 32x32 U tile is
// transposed in-LDS into the same UsT layout as before. grid 288, block 256.
__global__ __launch_bounds__(256) void k_g2uv(const float* __restrict__ U,
                                              const float* __restrict__ outTg,
                                              const float* __restrict__ dw,
                                              float* __restrict__ bij) {
    __shared__ float UsT[1024];    // [m32][chunk8 swizzled][4]
    __shared__ float OsT[5120];    // [co160][chunk8 swizzled][4]
    __shared__ float dwl[5120];
    __shared__ float sb[320];
    int blk = blockIdx.x, t = threadIdx.x;
    int tc = t & 15, tm = t >> 4;
    for (int idx = t; idx < 5120; idx += 256)
        dwl[idx] = dw[(size_t)blk * 5120 + idx];
    float acc[2][10] = {};
    for (int bs = 0; bs < 256; bs += 32) {
        __syncthreads();
        {   // stage UsT: in-LDS transpose of U[bs..bs+32)[blk*32..+32)
            // Same layout as the old UT path: for b-pos r, ik-local m:
            //   UsT[m*32 + ((r>>2)^(m&7))*4 + (r&3)] = U[(bs+r)*9216 + blk*32 + m]
            int r = t >> 3, c4 = t & 7;
            float4 v = *(const float4*)&U[(size_t)(bs + r) * 9216 + blk * 32 + c4 * 4];
            int hi = ((r >> 2)) , lo = (r & 3);
            int m0 = c4 * 4;
            UsT[(m0 + 0) * 32 + ((hi ^ ((m0 + 0) & 7)) << 2) + lo] = v.x;
            UsT[(m0 + 1) * 32 + ((hi ^ ((m0 + 1) & 7)) << 2) + lo] = v.y;
            UsT[(m0 + 2) * 32 + ((hi ^ ((m0 + 2) & 7)) << 2) + lo] = v.z;
            UsT[(m0 + 3) * 32 + ((hi ^ ((m0 + 3) & 7)) << 2) + lo] = v.w;
        }
        #pragma unroll
        for (int pass = 0; pass < 5; pass++) {
            int s = t + pass * 256;
            int co = s >> 3, p = s & 7;
            int kq = p ^ (co & 7);
            *(float4*)&OsT[s * 4] =
                *(const float4*)&outTg[(size_t)co * 256 + bs + kq * 4];
        }
        __syncthreads();
        float a0[32], a1[32];
        int m0 = tm * 2, m1 = tm * 2 + 1;
        #pragma unroll
        for (int kq = 0; kq < 8; kq++) {
            float4 v0 = *(const float4*)&UsT[m0 * 32 + ((kq ^ (m0 & 7)) << 2)];
            float4 v1 = *(const float4*)&UsT[m1 * 32 + ((kq ^ (m1 & 7)) << 2)];
            a0[kq * 4 + 0] = v0.x; a0[kq * 4 + 1] = v0.y; a0[kq * 4 + 2] = v0.z; a0[kq * 4 + 3] = v0.w;
            a1[kq * 4 + 0] = v1.x; a1[kq * 4 + 1] = v1.y; a1[kq * 4 + 2] = v1.z; a1[kq * 4 + 3] = v1.w;
        }
        #pragma unroll
        for (int j = 0; j < 10; j++) {
            int co = tc + 16 * j;
            int cx = co & 7, cbase = co * 32;
            #pragma unroll
            for (int kq = 0; kq < 8; kq++) {
                float4 wv = *(const float4*)&OsT[cbase + ((kq ^ cx) << 2)];
                acc[0][j] += a0[kq * 4 + 0] * wv.x; acc[0][j] += a0[kq * 4 + 1] * wv.y;
                acc[0][j] += a0[kq * 4 + 2] * wv.z; acc[0][j] += a0[kq * 4 + 3] * wv.w;
                acc[1][j] += a1[kq * 4 + 0] * wv.x; acc[1][j] += a1[kq * 4 + 1] * wv.y;
                acc[1][j] += a1[kq * 4 + 2] * wv.z; acc[1][j] += a1[kq * 4 + 3] * wv.w;
            }
        }
    }
    // contract with dw over o (=tc) per (ik_local, c)
    #pragma unroll
    for (int r = 0; r < 2; r++) {
        int ik_l = tm * 2 + r;
        int i_l = ik_l >> 3, k = ik_l & 7;
        #pragma unroll
        for (int j = 0; j < 10; j++) {
            float v = acc[r][j] * dwl[i_l * 1280 + (j * 16 + tc) * 8 + k];
            v += __shfl_down(v, 8, 16);
            v += __shfl_down(v, 4, 16);
            v += __shfl_down(v, 2, 16);
            v += __shfl_down(v, 1, 16);
            if (tc == 0) sb[ik_l * 10 + j] = v;
        }
    }
    __syncthreads();
    if (t < 40) {
        int i_l = t / 10, c = t % 10;
        float s = 0.f;
        #pragma unroll
        for (int kk = 0; kk < 8; kk++) s += sb[(i_l * 8 + kk) * 10 + c];
        size_t o = (size_t)(blk * 4 + i_l) * 10 + c;
        bij[o] += s * (1.0f / 256.0f);
    }
}

extern "C" void kernel_launch(void* const* d_in, const int* in_sizes, int n_in,
                              void* d_out, int out_size, void* d_ws, size_t ws_size,
                              hipStream_t stream) {
    const float* x      = (const float*)d_in[0];
    const float* conv_w = (const float*)d_in[1];
    const float* conv_b = (const float*)d_in[2];
    const float* prim_w = (const float*)d_in[3];
    const float* prim_b = (const float*)d_in[4];
    const float* dw     = (const float*)d_in[5];

    char* wsb = (char*)d_ws;
    unsigned short* h  = (unsigned short*)(wsb);
    unsigned short* wt = (unsigned short*)(wsb + 52428800);
    float* pp0  = (float*)(wsb + 63045632);
    float* pp1  = (float*)(wsb + 72482816);
    float* U    = (float*)(wsb + 81920000);
    float* dwT2 = (float*)(wsb + 91357184);
    float* pp3  = (float*)(wsb + 91357184);    // aliases dwT2 + part head
    float* part = (float*)(wsb + 97255424);
    float* csm  = (float*)(wsb + 102498304);
    float* bij  = (float*)(wsb + 102544384);
    float* outT = (float*)(wsb + 102590464);
    float* outw = (float*)(wsb + 102754304);
    float* pp2  = (float*)(wsb + 102918144);   // former UT region

    k_pre<<<4096, 256, 0, stream>>>(x, conv_w, conv_b, prim_w, h, wt);
    k_conv2m<<<dim3(96, 2, 4), 256, 0, stream>>>(h, wt, pp0, pp1, pp2, pp3);
    k_squash1<<<2048, 256, 0, stream>>>(pp0, pp1, pp2, pp3, prim_b, U);
    // dwT2 written only after squash1 consumed pp3
    k_dwt2<<<160, 256, 0, stream>>>(dw, dwT2);
    hipMemsetAsync(bij, 0, 11520 * sizeof(float), stream);

    // iter 0 (b_ij = 0 -> uniform c)
    k_gemm1<<<dim3(8, 32), 256, 0, stream>>>(U, dwT2, csm, part, 1);
    k_redsq<<<256, 256, 0, stream>>>(part, outw, outT, 1);
    k_g2uv<<<288, 256, 0, stream>>>(U, outT, dw, bij);
    k_softmax<<<10, 256, 0, stream>>>(bij, csm);
    // iter 1
    k_gemm1<<<dim3(8, 32), 256, 0, stream>>>(U, dwT2, csm, part, 0);
    k_redsq<<<256, 256, 0, stream>>>(part, outw, outT, 1);
    k_g2uv<<<288, 256, 0, stream>>>(U, outT, dw, bij);
    k_softmax<<<10, 256, 0, stream>>>(bij, csm);
    // iter 2
    k_gemm1<<<dim3(8, 32), 256, 0, stream>>>(U, dwT2, csm, part, 0);
    k_redsq<<<256, 256, 0, stream>>>(part, (float*)d_out, outT, 0);
}